// Round 6
// baseline (5522.577 us; speedup 1.0000x reference)
//
#include <hip/hip_runtime.h>
#include <hip/hip_bf16.h>
#include <math.h>

// ---- problem constants ----
#define V    32000
#define E    512
#define NH   8
#define DH   64
#define NL   2
#define FF   2048
#define MAXLEN 24
#define S    48
#define B    8
#define TRANS 14
#define INIT 12      // TRANS - 2
#define LF   35      // INIT + MAXLEN - 1

#define NB   256     // persistent grid blocks (1/CU, co-resident)
#define NT   512     // threads per block (8 waves)

typedef float f4 __attribute__((ext_vector_type(4)));

__device__ inline float wsum(float v) {
#pragma unroll
  for (int off = 32; off; off >>= 1) v += __shfl_xor(v, off);
  return v;
}
__device__ inline float wmax(float v) {
#pragma unroll
  for (int off = 32; off; off >>= 1) v = fmaxf(v, __shfl_xor(v, off));
  return v;
}

// ---- coherence-point (relaxed agent) helpers ----
__device__ inline float ldc(const float* p) {
  return __hip_atomic_load(p, __ATOMIC_RELAXED, __HIP_MEMORY_SCOPE_AGENT);
}
__device__ inline void stc(float* p, float v) {
  __hip_atomic_store(p, v, __ATOMIC_RELAXED, __HIP_MEMORY_SCOPE_AGENT);
}
__device__ inline float2 ldc8(const float* p) {
  union { unsigned long long u; float2 f; } c;
  c.u = __hip_atomic_load((const unsigned long long*)p, __ATOMIC_RELAXED, __HIP_MEMORY_SCOPE_AGENT);
  return c.f;
}
__device__ inline void stc8(float* p, float x, float y) {
  union { unsigned long long u; float f[2]; } c; c.f[0] = x; c.f[1] = y;
  __hip_atomic_store((unsigned long long*)p, c.u, __ATOMIC_RELAXED, __HIP_MEMORY_SCOPE_AGENT);
}
__device__ inline int ldci(const int* p) {
  return __hip_atomic_load(p, __ATOMIC_RELAXED, __HIP_MEMORY_SCOPE_AGENT);
}

// L2-bypass streaming load of 8 f4 (cache-policy bits only -> functionally safe)
__device__ inline void ld8_bypass(const float* p, f4* w) {
  asm volatile(
      "global_load_dwordx4 %0, %8, off sc0 sc1 nt\n\t"
      "global_load_dwordx4 %1, %8, off offset:16 sc0 sc1 nt\n\t"
      "global_load_dwordx4 %2, %8, off offset:32 sc0 sc1 nt\n\t"
      "global_load_dwordx4 %3, %8, off offset:48 sc0 sc1 nt\n\t"
      "global_load_dwordx4 %4, %8, off offset:64 sc0 sc1 nt\n\t"
      "global_load_dwordx4 %5, %8, off offset:80 sc0 sc1 nt\n\t"
      "global_load_dwordx4 %6, %8, off offset:96 sc0 sc1 nt\n\t"
      "global_load_dwordx4 %7, %8, off offset:112 sc0 sc1 nt\n\t"
      "s_waitcnt vmcnt(0)"
      : "=&v"(w[0]), "=&v"(w[1]), "=&v"(w[2]), "=&v"(w[3]),
        "=&v"(w[4]), "=&v"(w[5]), "=&v"(w[6]), "=&v"(w[7])
      : "v"(p));
}

#define CMB(v, idx, ov, oi) do { if ((ov) > (v) || ((ov) == (v) && (oi) < (idx))) { (v) = (ov); (idx) = (oi); } } while (0)

// ================= prefill kernels (rounds 1-5, proven) =================

__global__ void embed_init_k(const int* __restrict__ transform, const float* __restrict__ emb,
                             float* __restrict__ xbuf) {
  int t = blockIdx.x;
  int pos = t >> 3, b = t & 7;
  int tok = transform[(1 + pos) * B + b];
  for (int d = threadIdx.x; d < E; d += blockDim.x) {
    double div = exp(-log(10000.0) * (double)(d & ~1) / (double)E);
    double ang = (double)pos * div;
    float pe = (d & 1) ? (float)cos(ang) : (float)sin(ang);
    xbuf[(size_t)t * E + d] = emb[(size_t)tok * E + d] + pe;
  }
}

template <int K>
__global__ __launch_bounds__(256) void gemm_k(
    const float* __restrict__ x, const float* __restrict__ W, const float* __restrict__ bias,
    int ntok, int nout, int route, int relu,
    float* __restrict__ out0, float* __restrict__ out1, float* __restrict__ out2) {
  constexpr int K4 = K / 4;
  constexpr int J  = K / 256;
  __shared__ float4 xt[8][K4];
  const int tid = threadIdx.x;
  const int lane = tid & 63;
  const int o = blockIdx.x * 4 + (tid >> 6);

  float4 wr[J];
  if (o < nout) {
    const float4* Wr = (const float4*)(W + (size_t)o * K);
#pragma unroll
    for (int j = 0; j < J; ++j) wr[j] = Wr[lane + 64 * j];
  }

  const int ng = ntok >> 3;
  for (int g = 0; g < ng; ++g) {
    if (g) __syncthreads();
    const float4* xg = (const float4*)(x + (size_t)g * 8 * K);
    float4* xf = &xt[0][0];
    for (int i = tid; i < 8 * K4; i += 256) xf[i] = xg[i];
    __syncthreads();
    if (o < nout) {
      float acc[8] = {0, 0, 0, 0, 0, 0, 0, 0};
#pragma unroll
      for (int j = 0; j < J; ++j) {
        float4 w = wr[j];
#pragma unroll
        for (int tt = 0; tt < 8; ++tt) {
          float4 xv = xt[tt][lane + 64 * j];
          acc[tt] += w.x * xv.x + w.y * xv.y + w.z * xv.z + w.w * xv.w;
        }
      }
#pragma unroll
      for (int tt = 0; tt < 8; ++tt) acc[tt] = wsum(acc[tt]);
      if (lane == 0) {
        float bo = bias[o];
#pragma unroll
        for (int tt = 0; tt < 8; ++tt) {
          float v = acc[tt] + bo;
          if (relu) v = fmaxf(v, 0.f);
          int t = g * 8 + tt;
          if (route == 0) {
            out0[(size_t)t * nout + o] = v;
          } else if (route == 1) {
            if (o < E) out0[(size_t)t * E + o] = v;
            else if (o < 2 * E) out1[(size_t)t * E + (o - E)] = v;
            else out2[(size_t)t * E + (o - 2 * E)] = v;
          } else {
            if (o < E) out0[(size_t)t * E + o] = v;
            else out1[(size_t)t * E + (o - E)] = v;
          }
        }
      }
    }
  }
}

__global__ __launch_bounds__(256) void attn_k(
    const float* __restrict__ q, const float* __restrict__ Kc, const float* __restrict__ Vc,
    float* __restrict__ outp, int p0, int nq, int nk_fixed, int causal) {
  const int tid = threadIdx.x;
  const int lane = tid & 63;
  const int u = blockIdx.x * 4 + (tid >> 6);
  if (u >= nq * 64) return;
  const int qi = u >> 6;
  const int r = u & 63;
  const int b = r >> 3, h = r & 7;
  const int nk = causal ? (p0 + qi + 1) : nk_fixed;

  const size_t qoff = (size_t)(qi * B + b) * E + h * DH + lane;
  const float qv = q[qoff];

  float myscore = -INFINITY;
  for (int k = 0; k < nk; ++k) {
    float prod = qv * Kc[(size_t)(k * B + b) * E + h * DH + lane];
    prod = wsum(prod);
    if (lane == k) myscore = prod * 0.125f;
  }
  float m = wmax(myscore);
  float p = (lane < nk) ? expf(myscore - m) : 0.f;
  float denom = wsum(p);
  float a = p / denom;

  float oacc = 0.f;
  for (int k = 0; k < nk; ++k) {
    float ak = __shfl(a, k);
    oacc = fmaf(ak, Vc[(size_t)(k * B + b) * E + h * DH + lane], oacc);
  }
  outp[qoff] = oacc;
}

__global__ __launch_bounds__(256) void add_ln_k(
    const float* __restrict__ xa, const float* __restrict__ xb,
    const float* __restrict__ g, const float* __restrict__ beta,
    float* __restrict__ outp, int ntok) {
  const int tid = threadIdx.x, lane = tid & 63;
  const int t = blockIdx.x * 4 + (tid >> 6);
  if (t >= ntok) return;
  float v[8];
  float s = 0.f;
#pragma unroll
  for (int j = 0; j < 8; ++j) {
    int d = lane + 64 * j;
    v[j] = xa[(size_t)t * E + d] + xb[(size_t)t * E + d];
    s += v[j];
  }
  s = wsum(s);
  float mean = s * (1.f / 512.f);
  float d2 = 0.f;
#pragma unroll
  for (int j = 0; j < 8; ++j) { float dd = v[j] - mean; d2 += dd * dd; }
  d2 = wsum(d2);
  float inv = 1.f / sqrtf(d2 * (1.f / 512.f) + 1e-5f);
#pragma unroll
  for (int j = 0; j < 8; ++j) {
    int d = lane + 64 * j;
    outp[(size_t)t * E + d] = (v[j] - mean) * inv * g[d] + beta[d];
  }
}

// ================= persistent decode v3: LDS-resident weights, grid-wide stages =================
// s_w layout (floats): per block slice of ALL decoder weights, loaded once.
#define B_QKV 0        // 2l x 6 rows x 512       rows r=bid*6+j of sa_w[l]
#define B_OW  6144     // 2l x 2 rows x 512       rows r=bid*2+j of sa_ow[l]
#define B_CQ  8192     // 2l x 2 rows x 512       rows r=bid*2+j of ca_w[l] (q section)
#define B_COW 10240    // 2l x 2 rows x 512       rows r=bid*2+j of ca_ow[l]
#define B_FF1 12288    // 2l x 8 rows x 512       rows r=bid*8+j of ff1_w[l]
#define B_FF2 20480    // 2l x 8 x 512            (kc=bid>>6, row=(bid&63)*8+j, cols kc*512..)
#define SW_TOT 28672

__global__ __launch_bounds__(NT, 1) void decode_persist_k(
    const float* __restrict__ emb,
    const float* __restrict__ sa_w, const float* __restrict__ sa_b,
    const float* __restrict__ sa_ow, const float* __restrict__ sa_ob,
    const float* __restrict__ ca_w, const float* __restrict__ ca_b,
    const float* __restrict__ ca_ow, const float* __restrict__ ca_ob,
    const float* __restrict__ ff1_w, const float* __restrict__ ff1_b,
    const float* __restrict__ ff2_w, const float* __restrict__ ff2_b,
    const float* __restrict__ ln_g, const float* __restrict__ ln_b,
    const float* __restrict__ out_w, const float* __restrict__ out_b,
    float* __restrict__ kself, float* __restrict__ vself,
    const float* __restrict__ kcross, const float* __restrict__ vcross,
    float* __restrict__ xstep, float* __restrict__ qbuf, float* __restrict__ attbuf,
    float* __restrict__ rawbuf, float* __restrict__ x1buf, float* __restrict__ x2buf,
    float* __restrict__ x3buf, float* __restrict__ ybuf, float* __restrict__ hbuf,
    float* __restrict__ pbuf, float* __restrict__ amaxbuf,
    float* __restrict__ outp, int* __restrict__ bar) {
  __shared__ __align__(16) float s_w[SW_TOT];   // 112 KB weight slice
  __shared__ __align__(16) float s_x[8 * E];    // 16 KB staging A
  __shared__ __align__(16) float s_y[8 * E];    // 16 KB staging B
  __shared__ __align__(16) float s_q2[64];
  __shared__ float s_rv[NT];
  __shared__ int   s_ri[NT];
  __shared__ float s_pv[8][8];
  __shared__ int   s_pi[8][8];

  const int tid  = threadIdx.x;
  const int lane = tid & 63;
  const int wv   = tid >> 6;          // wave 0..7
  const int g4   = lane >> 2;
  const int s4   = lane & 3;
  const int bid  = blockIdx.x;
  int gen = 0;

  // ---- 2-level grid barrier: 32 sharded counters, 32-lane parallel poll ----
  auto gbar = [&]() {
    ++gen;
    __syncthreads();                  // drains each wave's stc (vmcnt 0)
    if (tid == 0)
      __hip_atomic_fetch_add(&bar[(bid & 31) * 32], 1, __ATOMIC_RELAXED, __HIP_MEMORY_SCOPE_AGENT);
    if (wv == 0) {
      const int target = gen * 8;     // 256 blocks / 32 shards
      for (;;) {
        int c = ldci(&bar[(lane & 31) * 32]);
        if (__all(c >= target)) break;
        __builtin_amdgcn_s_sleep(2);
      }
    }
    __syncthreads();
  };

  // ---- stage a [8][512] vector set from MALL into LDS ----
  auto stage_in = [&](float* dst, const float* src) {
    for (int k = tid; k < 2048; k += NT) {
      float2 vv = ldc8(src + 2 * k);
      dst[2 * k] = vv.x; dst[2 * k + 1] = vv.y;
    }
  };
  // ---- s_x[wv] = LN(s_x[wv] + s_y[wv]); wave wv = batch wv ----
  auto lnstage = [&](int lnidx) {
    const float* gg = ln_g + (size_t)lnidx * E;
    const float* be = ln_b + (size_t)lnidx * E;
    float v[8]; float sum = 0.f;
#pragma unroll
    for (int j = 0; j < 8; ++j) {
      int d = lane + 64 * j;
      v[j] = s_x[wv * E + d] + s_y[wv * E + d];
      sum += v[j];
    }
    sum = wsum(sum);
    float mean = sum * (1.f / 512.f);
    float d2 = 0.f;
#pragma unroll
    for (int j = 0; j < 8; ++j) { float dd = v[j] - mean; d2 += dd * dd; }
    d2 = wsum(d2);
    float inv = 1.f / sqrtf(d2 * (1.f / 512.f) + 1e-5f);
#pragma unroll
    for (int j = 0; j < 8; ++j) {
      int d = lane + 64 * j;
      s_x[wv * E + d] = (v[j] - mean) * inv * gg[d] + be[d];
    }
    __syncthreads();
  };
  // ---- blocks 0..7 publish s_x[batch=bid] to a MALL buffer ----
  auto publish = [&](float* dst) {
    for (int k = tid; k < 256; k += NT)
      stc8(&dst[bid * E + 2 * k], s_x[bid * E + 2 * k], s_x[bid * E + 2 * k + 1]);
  };
  // ---- 2 rows (bid*2+{0,1}) x 8 batches, K=512 from s_x; + bias; stc dst[b*512+r] ----
  auto proj2 = [&](int wbase, const float* biasp, float* dst) {
    const int row = wv & 1;
    const int r = bid * 2 + row;
    const f4* wp = (const f4*)&s_w[wbase + row * 512];
    f4 w0 = wp[lane], w1 = wp[lane + 64];
    float bias = biasp[r];
#pragma unroll
    for (int half = 0; half < 2; ++half) {
      int b = (wv >> 1) + half * 4;
      const f4* x4 = (const f4*)&s_x[b * E];
      f4 a = w0 * x4[lane] + w1 * x4[lane + 64];
      float acc = a.x + a.y + a.z + a.w;
      acc = wsum(acc);
      if (lane == 0) stc(&dst[b * E + r], acc + bias);
    }
  };
  // ---- attention for (b,h)=(bid>>3, bid&7); q from qbuf; out -> attbuf ----
  auto attn_stage = [&](const float* Kbase, const float* Vbase, int nk) {
    const int b = bid >> 3, h = bid & 7;
    if (wv == 0) {
      s_q2[lane] = ldc(&qbuf[b * E + h * DH + lane]);
      float sc = -INFINITY;
      if (lane < nk) {
        const f4* Kr = (const f4*)(Kbase + ((size_t)lane * B + b) * E + h * DH);
        const f4* Qp = (const f4*)s_q2;
        float a0 = 0.f;
#pragma unroll
        for (int u = 0; u < 16; ++u) {
          f4 kv = Kr[u], qv = Qp[u];
          a0 += kv.x * qv.x + kv.y * qv.y + kv.z * qv.z + kv.w * qv.w;
        }
        sc = a0 * 0.125f;
      }
      float m = wmax(sc);
      float e = (lane < nk) ? expf(sc - m) : 0.f;
      float den = wsum(e);
      float aa = e / den;
      float oa = 0.f;
#pragma unroll 4
      for (int k2 = 0; k2 < nk; ++k2) {
        float ak = __shfl(aa, k2);
        oa = fmaf(ak, Vbase[((size_t)k2 * B + b) * E + h * DH + lane], oa);
      }
      stc(&attbuf[b * E + h * DH + lane], oa);
    }
  };

  // ================= one-time: preload weight slices into LDS =================
  {
    auto cprow = [&](const float* src, int dstf) {
      f4* d = (f4*)&s_w[dstf];
      const f4* s = (const f4*)src;
      for (int k = tid; k < 128; k += NT) d[k] = s[k];
    };
    const int kc = bid >> 6;
    for (int l = 0; l < NL; ++l) {
      for (int j = 0; j < 6; ++j)
        cprow(sa_w + ((size_t)l * 1536 + bid * 6 + j) * E, B_QKV + (l * 6 + j) * 512);
      for (int j = 0; j < 2; ++j) {
        cprow(sa_ow + ((size_t)l * 512 + bid * 2 + j) * E, B_OW + (l * 2 + j) * 512);
        cprow(ca_w + ((size_t)l * 1536 + bid * 2 + j) * E, B_CQ + (l * 2 + j) * 512);
        cprow(ca_ow + ((size_t)l * 512 + bid * 2 + j) * E, B_COW + (l * 2 + j) * 512);
      }
      for (int j = 0; j < 8; ++j) {
        cprow(ff1_w + ((size_t)l * FF + bid * 8 + j) * E, B_FF1 + (l * 8 + j) * 512);
        cprow(ff2_w + ((size_t)l * 512 + (bid & 63) * 8 + j) * FF + kc * 512,
              B_FF2 + (l * 8 + j) * 512);
      }
    }
    __syncthreads();
  }

  // ================= 23 autoregressive steps =================
  for (int i = 0; i < MAXLEN - 1; ++i) {
    const int p = INIT + i;

    // ---- stage A: per-batch argmax + embed (blocks 0..7) ----
    if (bid < 8) {
      const int b = bid;
      if (i == 0) {
        const float* row = outp + ((size_t)(INIT - 1) * B + b) * V;
        float bv = -INFINITY; int bi = 0x7fffffff;
        for (int j2 = tid; j2 < V / 2; j2 += NT) {
          float2 vv = ldc8(row + 2 * j2);
          CMB(bv, bi, vv.x, 2 * j2);
          CMB(bv, bi, vv.y, 2 * j2 + 1);
        }
        s_rv[tid] = bv; s_ri[tid] = bi;
      } else {
        if (tid < 256) {
          float2 pr = ldc8(&amaxbuf[(size_t)(tid * 8 + b) * 2]);
          s_rv[tid] = pr.x; s_ri[tid] = (int)pr.y;
        } else { s_rv[tid] = -INFINITY; s_ri[tid] = 0x7fffffff; }
      }
      __syncthreads();
      for (int st2 = NT / 2; st2; st2 >>= 1) {
        if (tid < st2) {
          float ov = s_rv[tid + st2]; int oi = s_ri[tid + st2];
          CMB(s_rv[tid], s_ri[tid], ov, oi);
        }
        __syncthreads();
      }
      const int tok = s_ri[0];
      if (tid < 256) {
        int d0 = tid * 2;
        float e0 = emb[(size_t)tok * E + d0];
        float e1 = emb[(size_t)tok * E + d0 + 1] + 1.0f;   // + pe[0]
        stc8(&xstep[(size_t)b * E + d0], e0, e1);
      }
    }
    gbar();

    for (int l = 0; l < NL; ++l) {
      // ---- S1: QKV (rows bid*6..+5, all 8 batches) ----
      if (l == 0) {
        stage_in(s_x, xstep);
        __syncthreads();
      } else {
        stage_in(s_x, x2buf); stage_in(s_y, ybuf);
        __syncthreads();
        lnstage(2);                      // x3 of layer 0
        if (bid < 8) publish(x3buf);
      }
      if (wv < 6) {
        const int r = bid * 6 + wv;
        const int sec = r >> 9, off = r & 511;
        const f4* wp = (const f4*)&s_w[B_QKV + (l * 6 + wv) * 512];
        f4 w0 = wp[lane], w1 = wp[lane + 64];
        float bias = sa_b[(size_t)l * 1536 + r];
#pragma unroll
        for (int b = 0; b < 8; ++b) {
          const f4* x4 = (const f4*)&s_x[b * E];
          f4 a = w0 * x4[lane] + w1 * x4[lane + 64];
          float acc = a.x + a.y + a.z + a.w;
          acc = wsum(acc);
          if (lane == 0) {
            acc += bias;
            if (sec == 0) stc(&qbuf[b * E + off], acc);
            else if (sec == 1) stc(&kself[((size_t)(l * LF + p) * B + b) * E + off], acc);
            else stc(&vself[((size_t)(l * LF + p) * B + b) * E + off], acc);
          }
        }
      }
      gbar();
      // ---- S2: self-attention (keys 0..p) ----
      if (bid < 64) attn_stage(kself + (size_t)l * LF * B * E, vself + (size_t)l * LF * B * E, p + 1);
      gbar();
      // ---- S3: self out-proj ----
      stage_in(s_x, attbuf);
      __syncthreads();
      proj2(B_OW + l * 1024, sa_ob + (size_t)l * 512, rawbuf);
      gbar();
      // ---- S4: x1 = LN(x + raw); publish x1; cross-Q proj ----
      stage_in(s_x, (l == 0) ? xstep : x3buf); stage_in(s_y, rawbuf);
      __syncthreads();
      lnstage(l * 3 + 0);
      if (bid < 8) publish(x1buf);
      proj2(B_CQ + l * 1024, ca_b + (size_t)l * 1536, qbuf);
      gbar();
      // ---- S5: cross-attention (48 keys) ----
      if (bid < 64) attn_stage(kcross + (size_t)l * S * B * E, vcross + (size_t)l * S * B * E, S);
      gbar();
      // ---- S6: cross out-proj ----
      stage_in(s_x, attbuf);
      __syncthreads();
      proj2(B_COW + l * 1024, ca_ob + (size_t)l * 512, rawbuf);
      gbar();
      // ---- S7: x2 = LN(x1 + raw); publish x2; ff1 (relu) ----
      stage_in(s_x, x1buf); stage_in(s_y, rawbuf);
      __syncthreads();
      lnstage(l * 3 + 1);
      if (bid < 8) publish(x2buf);
      {
        const int r = bid * 8 + wv;
        const f4* wp = (const f4*)&s_w[B_FF1 + (l * 8 + wv) * 512];
        f4 w0 = wp[lane], w1 = wp[lane + 64];
        float bias = ff1_b[(size_t)l * FF + r];
#pragma unroll
        for (int b = 0; b < 8; ++b) {
          const f4* x4 = (const f4*)&s_x[b * E];
          f4 a = w0 * x4[lane] + w1 * x4[lane + 64];
          float acc = a.x + a.y + a.z + a.w;
          acc = wsum(acc);
          if (lane == 0) stc(&hbuf[b * FF + r], fmaxf(acc + bias, 0.f));
        }
      }
      gbar();
      // ---- S8: ff2 partial (kc = bid>>6, rows (bid&63)*8..+7) ----
      {
        const int kc = bid >> 6;
        for (int k = tid; k < 2048; k += NT) {
          int b = k >> 8, d2 = (k & 255) * 2;
          float2 vv = ldc8(&hbuf[b * FF + kc * 512 + d2]);
          s_x[b * E + d2] = vv.x; s_x[b * E + d2 + 1] = vv.y;
        }
        __syncthreads();
        const int rowf = (bid & 63) * 8 + wv;
        const f4* wp = (const f4*)&s_w[B_FF2 + (l * 8 + wv) * 512];
        f4 w0 = wp[lane], w1 = wp[lane + 64];
#pragma unroll
        for (int b = 0; b < 8; ++b) {
          const f4* x4 = (const f4*)&s_x[b * E];
          f4 a = w0 * x4[lane] + w1 * x4[lane + 64];
          float acc = a.x + a.y + a.z + a.w;
          acc = wsum(acc);
          if (lane == 0) stc(&pbuf[(size_t)(kc * 512 + rowf) * 8 + b], acc);
        }
      }
      gbar();
      // ---- S9: ff2 reduce -> ybuf ----
      {
        const int row = bid * 2 + (wv & 1);
#pragma unroll
        for (int half = 0; half < 2; ++half) {
          int b = (wv >> 1) + half * 4;
          if (lane == 0) {
            float y = ff2_b[(size_t)l * 512 + row];
#pragma unroll
            for (int kc = 0; kc < 4; ++kc) y += ldc(&pbuf[(size_t)(kc * 512 + row) * 8 + b]);
            stc(&ybuf[b * E + row], y);
          }
        }
      }
      gbar();
    }

    // ---- logits: x3 = LN(x2 + y); 125 rows/block streamed sc1; partial argmax ----
    stage_in(s_x, x2buf); stage_in(s_y, ybuf);
    __syncthreads();
    lnstage(5);
    {
      const int idx = wv * 16 + g4;            // 0..127
      const bool valid = idx < 125;
      const int r = bid * 125 + idx;
      float acc[8] = {0, 0, 0, 0, 0, 0, 0, 0};
      if (valid) {
        const float* wrow = out_w + (size_t)r * E + s4 * 128;
#pragma unroll
        for (int seg = 0; seg < 4; ++seg) {
          f4 w8[8];
          ld8_bypass(wrow + seg * 32, w8);
#pragma unroll
          for (int b = 0; b < 8; ++b) {
            const f4* x4 = (const f4*)&s_x[b * E + s4 * 128 + seg * 32];
#pragma unroll
            for (int q = 0; q < 8; ++q) {
              f4 xx = x4[q];
              acc[b] += w8[q].x * xx.x + w8[q].y * xx.y + w8[q].z * xx.z + w8[q].w * xx.w;
            }
          }
        }
#pragma unroll
        for (int b = 0; b < 8; ++b) {
          acc[b] += __shfl_xor(acc[b], 1);
          acc[b] += __shfl_xor(acc[b], 2);
          acc[b] += out_b[r];
        }
        if (s4 == 0) {
#pragma unroll
          for (int b = 0; b < 8; ++b)
            stc(&outp[((size_t)p * B + b) * V + r], acc[b]);
        }
      }
#pragma unroll
      for (int b = 0; b < 8; ++b) {
        float v = valid ? acc[b] : -INFINITY;
        int ix = valid ? r : 0x7fffffff;
#pragma unroll
        for (int off = 1; off < 64; off <<= 1) {
          float ov = __shfl_xor(v, off); int oi = __shfl_xor(ix, off);
          CMB(v, ix, ov, oi);
        }
        if (lane == 0) { s_pv[wv][b] = v; s_pi[wv][b] = ix; }
      }
      __syncthreads();
      if (wv == 0) {
        int b = lane & 7, w2 = lane >> 3;
        float v = s_pv[w2][b]; int ix = s_pi[w2][b];
#pragma unroll
        for (int off = 8; off < 64; off <<= 1) {
          float ov = __shfl_xor(v, off); int oi = __shfl_xor(ix, off);
          CMB(v, ix, ov, oi);
        }
        if (lane < 8) stc8(&amaxbuf[(size_t)(bid * 8 + lane) * 2], v, (float)ix);
      }
    }
    gbar();
  }
}

extern "C" void kernel_launch(void* const* d_in, const int* in_sizes, int n_in,
                              void* d_out, int out_size, void* d_ws, size_t ws_size,
                              hipStream_t stream) {
  const float* enc       = (const float*)d_in[0];
  const int*   transform = (const int*)d_in[1];
  const float* emb       = (const float*)d_in[3];
  const float* sa_w  = (const float*)d_in[4];
  const float* sa_b  = (const float*)d_in[5];
  const float* sa_ow = (const float*)d_in[6];
  const float* sa_ob = (const float*)d_in[7];
  const float* ca_w  = (const float*)d_in[8];
  const float* ca_b  = (const float*)d_in[9];
  const float* ca_ow = (const float*)d_in[10];
  const float* ca_ob = (const float*)d_in[11];
  const float* ff1_w = (const float*)d_in[12];
  const float* ff1_b = (const float*)d_in[13];
  const float* ff2_w = (const float*)d_in[14];
  const float* ff2_b = (const float*)d_in[15];
  const float* ln_g  = (const float*)d_in[16];
  const float* ln_b  = (const float*)d_in[17];
  const float* out_w = (const float*)d_in[18];
  const float* out_b = (const float*)d_in[19];
  float* out = (float*)d_out;

  // workspace layout (floats)
  const size_t SELF_SZ  = (size_t)LF * B * E;    // 143360
  const size_t CROSS_SZ = (size_t)S * B * E;     // 196608
  float* ws     = (float*)d_ws;
  float* xbuf   = ws;                            // prefill embeddings [12*B, E]
  float* kself  = xbuf + (size_t)INIT * B * E;
  float* vself  = kself + NL * SELF_SZ;
  float* kcross = vself + NL * SELF_SZ;
  float* vcross = kcross + NL * CROSS_SZ;
  // persistent-kernel buffers
  float* xstep  = vcross + NL * CROSS_SZ;        // [8,512]
  float* qbuf   = xstep + 8 * E;
  float* attbuf = qbuf + 8 * E;
  float* rawbuf = attbuf + 8 * E;
  float* x1buf  = rawbuf + 8 * E;
  float* x2buf  = x1buf + 8 * E;
  float* x3buf  = x2buf + 8 * E;
  float* ybuf   = x3buf + 8 * E;
  float* hbuf   = ybuf + 8 * E;                  // [8,2048]
  float* pbuf   = hbuf + 8 * FF;                 // [4,512,8]
  float* amaxb  = pbuf + 4 * 512 * 8;            // [256,8,2]
  int*   bar    = (int*)(amaxb + 256 * 8 * 2);   // 32 shards x 128B
  // prefill activations (after persist buffers; no overlap)
  float* act1   = (float*)(bar + 1024);
  float* act2   = act1 + 96 * E;
  float* act3   = act2 + 96 * E;
  float* ffb    = act3 + 96 * E;                 // [96,FF]

  hipMemsetAsync(bar, 0, 4096, stream);

  // 1) initial embeddings (positions 0..11)
  embed_init_k<<<INIT * B, 128, 0, stream>>>(transform, emb, xbuf);

  // 2) cross-attn K/V caches
  for (int l = 0; l < NL; ++l) {
    gemm_k<E><<<(2 * E) / 4, 256, 0, stream>>>(
        enc, ca_w + ((size_t)l * 3 * E + E) * E, ca_b + (size_t)l * 3 * E + E,
        S * B, 2 * E, 2, 0, kcross + l * CROSS_SZ, vcross + l * CROSS_SZ, nullptr);
  }

  // 3) prefill positions 0..11 (multi-kernel, one-time)
  {
    const int p0 = 0, nq = INIT, ntok = nq * B;
    const float* xin = xbuf;
    for (int l = 0; l < NL; ++l) {
      const float* x = (l == 0) ? xin : act1;
      gemm_k<E><<<(3 * E) / 4, 256, 0, stream>>>(
          x, sa_w + (size_t)l * 3 * E * E, sa_b + (size_t)l * 3 * E, ntok, 3 * E, 1, 0,
          act2, kself + l * SELF_SZ, vself + l * SELF_SZ);
      attn_k<<<nq * 16, 256, 0, stream>>>(act2, kself + l * SELF_SZ, vself + l * SELF_SZ,
                                          act3, p0, nq, 0, 1);
      gemm_k<E><<<E / 4, 256, 0, stream>>>(
          act3, sa_ow + (size_t)l * E * E, sa_ob + (size_t)l * E, ntok, E, 0, 0, act2, nullptr, nullptr);
      add_ln_k<<<(ntok + 3) / 4, 256, 0, stream>>>(
          x, act2, ln_g + (size_t)l * 3 * E, ln_b + (size_t)l * 3 * E, act1, ntok);
      gemm_k<E><<<E / 4, 256, 0, stream>>>(
          act1, ca_w + (size_t)l * 3 * E * E, ca_b + (size_t)l * 3 * E, ntok, E, 0, 0, act2, nullptr, nullptr);
      attn_k<<<nq * 16, 256, 0, stream>>>(act2, kcross + l * CROSS_SZ, vcross + l * CROSS_SZ,
                                          act3, p0, nq, S, 0);
      gemm_k<E><<<E / 4, 256, 0, stream>>>(
          act3, ca_ow + (size_t)l * E * E, ca_ob + (size_t)l * E, ntok, E, 0, 0, act2, nullptr, nullptr);
      add_ln_k<<<(ntok + 3) / 4, 256, 0, stream>>>(
          act1, act2, ln_g + (size_t)l * 3 * E + E, ln_b + (size_t)l * 3 * E + E, act1, ntok);
      gemm_k<E><<<FF / 4, 256, 0, stream>>>(
          act1, ff1_w + (size_t)l * FF * E, ff1_b + (size_t)l * FF, ntok, FF, 0, 1, ffb, nullptr, nullptr);
      gemm_k<FF><<<E / 4, 256, 0, stream>>>(
          ffb, ff2_w + (size_t)l * E * FF, ff2_b + (size_t)l * E, ntok, E, 0, 0, act2, nullptr, nullptr);
      add_ln_k<<<(ntok + 3) / 4, 256, 0, stream>>>(
          act1, act2, ln_g + (size_t)l * 3 * E + 2 * E, ln_b + (size_t)l * 3 * E + 2 * E, act1, ntok);
    }
    gemm_k<E><<<V / 4, 256, 0, stream>>>(
        act1, out_w, out_b, ntok, V, 0, 0, out, nullptr, nullptr);
  }

  // 4) persistent kernel: all 23 autoregressive steps
  decode_persist_k<<<NB, NT, 0, stream>>>(
      emb, sa_w, sa_b, sa_ow, sa_ob, ca_w, ca_b, ca_ow, ca_ob,
      ff1_w, ff1_b, ff2_w, ff2_b, ln_g, ln_b, out_w, out_b,
      kself, vself, kcross, vcross,
      xstep, qbuf, attbuf, rawbuf, x1buf, x2buf, x3buf, ybuf, hbuf, pbuf, amaxb,
      out, bar);
}

// Round 7
// 5474.025 us; speedup vs baseline: 1.0089x; 1.0089x over previous
//
#include <hip/hip_runtime.h>
#include <hip/hip_bf16.h>
#include <math.h>

// ---- problem constants ----
#define V    32000
#define E    512
#define NH   8
#define DH   64
#define NL   2
#define FF   2048
#define MAXLEN 24
#define S    48
#define B    8
#define TRANS 14
#define INIT 12      // TRANS - 2
#define LF   35      // INIT + MAXLEN - 1

#define NB   256     // persistent grid blocks (1/CU, co-resident)
#define NT   1024    // threads per block (16 waves)

typedef float f4 __attribute__((ext_vector_type(4)));

__device__ inline float wsum(float v) {
#pragma unroll
  for (int off = 32; off; off >>= 1) v += __shfl_xor(v, off);
  return v;
}
__device__ inline float wmax(float v) {
#pragma unroll
  for (int off = 32; off; off >>= 1) v = fmaxf(v, __shfl_xor(v, off));
  return v;
}

// ---- coherence-point (relaxed agent) helpers ----
__device__ inline float ldc(const float* p) {
  return __hip_atomic_load(p, __ATOMIC_RELAXED, __HIP_MEMORY_SCOPE_AGENT);
}
__device__ inline void stc(float* p, float v) {
  __hip_atomic_store(p, v, __ATOMIC_RELAXED, __HIP_MEMORY_SCOPE_AGENT);
}
__device__ inline float2 ldc8(const float* p) {
  union { unsigned long long u; float2 f; } c;
  c.u = __hip_atomic_load((const unsigned long long*)p, __ATOMIC_RELAXED, __HIP_MEMORY_SCOPE_AGENT);
  return c.f;
}
__device__ inline void stc8(float* p, float x, float y) {
  union { unsigned long long u; float f[2]; } c; c.f[0] = x; c.f[1] = y;
  __hip_atomic_store((unsigned long long*)p, c.u, __ATOMIC_RELAXED, __HIP_MEMORY_SCOPE_AGENT);
}
__device__ inline int ldci(const int* p) {
  return __hip_atomic_load(p, __ATOMIC_RELAXED, __HIP_MEMORY_SCOPE_AGENT);
}
__device__ inline void stci(int* p, int v) {
  __hip_atomic_store(p, v, __ATOMIC_RELAXED, __HIP_MEMORY_SCOPE_AGENT);
}

#define CMB(v, idx, ov, oi) do { if ((ov) > (v) || ((ov) == (v) && (oi) < (idx))) { (v) = (ov); (idx) = (oi); } } while (0)

// ================= prefill kernels (rounds 1-6, proven) =================

__global__ void embed_init_k(const int* __restrict__ transform, const float* __restrict__ emb,
                             float* __restrict__ xbuf) {
  int t = blockIdx.x;
  int pos = t >> 3, b = t & 7;
  int tok = transform[(1 + pos) * B + b];
  for (int d = threadIdx.x; d < E; d += blockDim.x) {
    double div = exp(-log(10000.0) * (double)(d & ~1) / (double)E);
    double ang = (double)pos * div;
    float pe = (d & 1) ? (float)cos(ang) : (float)sin(ang);
    xbuf[(size_t)t * E + d] = emb[(size_t)tok * E + d] + pe;
  }
}

template <int K>
__global__ __launch_bounds__(256) void gemm_k(
    const float* __restrict__ x, const float* __restrict__ W, const float* __restrict__ bias,
    int ntok, int nout, int route, int relu,
    float* __restrict__ out0, float* __restrict__ out1, float* __restrict__ out2) {
  constexpr int K4 = K / 4;
  constexpr int J  = K / 256;
  __shared__ float4 xt[8][K4];
  const int tid = threadIdx.x;
  const int lane = tid & 63;
  const int o = blockIdx.x * 4 + (tid >> 6);

  float4 wr[J];
  if (o < nout) {
    const float4* Wr = (const float4*)(W + (size_t)o * K);
#pragma unroll
    for (int j = 0; j < J; ++j) wr[j] = Wr[lane + 64 * j];
  }

  const int ng = ntok >> 3;
  for (int g = 0; g < ng; ++g) {
    if (g) __syncthreads();
    const float4* xg = (const float4*)(x + (size_t)g * 8 * K);
    float4* xf = &xt[0][0];
    for (int i = tid; i < 8 * K4; i += 256) xf[i] = xg[i];
    __syncthreads();
    if (o < nout) {
      float acc[8] = {0, 0, 0, 0, 0, 0, 0, 0};
#pragma unroll
      for (int j = 0; j < J; ++j) {
        float4 w = wr[j];
#pragma unroll
        for (int tt = 0; tt < 8; ++tt) {
          float4 xv = xt[tt][lane + 64 * j];
          acc[tt] += w.x * xv.x + w.y * xv.y + w.z * xv.z + w.w * xv.w;
        }
      }
#pragma unroll
      for (int tt = 0; tt < 8; ++tt) acc[tt] = wsum(acc[tt]);
      if (lane == 0) {
        float bo = bias[o];
#pragma unroll
        for (int tt = 0; tt < 8; ++tt) {
          float v = acc[tt] + bo;
          if (relu) v = fmaxf(v, 0.f);
          int t = g * 8 + tt;
          if (route == 0) {
            out0[(size_t)t * nout + o] = v;
          } else if (route == 1) {
            if (o < E) out0[(size_t)t * E + o] = v;
            else if (o < 2 * E) out1[(size_t)t * E + (o - E)] = v;
            else out2[(size_t)t * E + (o - 2 * E)] = v;
          } else {
            if (o < E) out0[(size_t)t * E + o] = v;
            else out1[(size_t)t * E + (o - E)] = v;
          }
        }
      }
    }
  }
}

__global__ __launch_bounds__(256) void attn_k(
    const float* __restrict__ q, const float* __restrict__ Kc, const float* __restrict__ Vc,
    float* __restrict__ outp, int p0, int nq, int nk_fixed, int causal) {
  const int tid = threadIdx.x;
  const int lane = tid & 63;
  const int u = blockIdx.x * 4 + (tid >> 6);
  if (u >= nq * 64) return;
  const int qi = u >> 6;
  const int r = u & 63;
  const int b = r >> 3, h = r & 7;
  const int nk = causal ? (p0 + qi + 1) : nk_fixed;

  const size_t qoff = (size_t)(qi * B + b) * E + h * DH + lane;
  const float qv = q[qoff];

  float myscore = -INFINITY;
  for (int k = 0; k < nk; ++k) {
    float prod = qv * Kc[(size_t)(k * B + b) * E + h * DH + lane];
    prod = wsum(prod);
    if (lane == k) myscore = prod * 0.125f;
  }
  float m = wmax(myscore);
  float p = (lane < nk) ? expf(myscore - m) : 0.f;
  float denom = wsum(p);
  float a = p / denom;

  float oacc = 0.f;
  for (int k = 0; k < nk; ++k) {
    float ak = __shfl(a, k);
    oacc = fmaf(ak, Vc[(size_t)(k * B + b) * E + h * DH + lane], oacc);
  }
  outp[qoff] = oacc;
}

__global__ __launch_bounds__(256) void add_ln_k(
    const float* __restrict__ xa, const float* __restrict__ xb,
    const float* __restrict__ g, const float* __restrict__ beta,
    float* __restrict__ outp, int ntok) {
  const int tid = threadIdx.x, lane = tid & 63;
  const int t = blockIdx.x * 4 + (tid >> 6);
  if (t >= ntok) return;
  float v[8];
  float s = 0.f;
#pragma unroll
  for (int j = 0; j < 8; ++j) {
    int d = lane + 64 * j;
    v[j] = xa[(size_t)t * E + d] + xb[(size_t)t * E + d];
    s += v[j];
  }
  s = wsum(s);
  float mean = s * (1.f / 512.f);
  float d2 = 0.f;
#pragma unroll
  for (int j = 0; j < 8; ++j) { float dd = v[j] - mean; d2 += dd * dd; }
  d2 = wsum(d2);
  float inv = 1.f / sqrtf(d2 * (1.f / 512.f) + 1e-5f);
#pragma unroll
  for (int j = 0; j < 8; ++j) {
    int d = lane + 64 * j;
    outp[(size_t)t * E + d] = (v[j] - mean) * inv * g[d] + beta[d];
  }
}

// ================= persistent decode v4 =================
// LDS-resident decoder weights, flag-slot grid barrier, redundant argmax/LN,
// residual stream held persistently in LDS (s_x). 17 barriers/step.
#define B_QKV 0        // 2l x 6 rows x 512
#define B_OW  6144     // 2l x 2 rows x 512
#define B_CQ  8192     // 2l x 2 rows x 512
#define B_COW 10240    // 2l x 2 rows x 512
#define B_FF1 12288    // 2l x 8 rows x 512
#define B_FF2 20480    // 4 rows x 2048 (layer = bid>>7)
#define SW_TOT 28672

__global__ __launch_bounds__(NT, 1) void decode_persist_k(
    const float* __restrict__ emb,
    const float* __restrict__ sa_w, const float* __restrict__ sa_b,
    const float* __restrict__ sa_ow, const float* __restrict__ sa_ob,
    const float* __restrict__ ca_w, const float* __restrict__ ca_b,
    const float* __restrict__ ca_ow, const float* __restrict__ ca_ob,
    const float* __restrict__ ff1_w, const float* __restrict__ ff1_b,
    const float* __restrict__ ff2_w, const float* __restrict__ ff2_b,
    const float* __restrict__ ln_g, const float* __restrict__ ln_b,
    const float* __restrict__ out_w, const float* __restrict__ out_b,
    float* __restrict__ kself, float* __restrict__ vself,
    const float* __restrict__ kcross, const float* __restrict__ vcross,
    float* __restrict__ qbuf, float* __restrict__ attbuf, float* __restrict__ rawbuf,
    float* __restrict__ hbuf, float* __restrict__ amaxbuf,
    float* __restrict__ outp, int* __restrict__ bar) {
  __shared__ __align__(16) float s_w[SW_TOT];   // 112 KB weight slice
  __shared__ __align__(16) float s_x[8 * E];    // residual stream (persistent)
  __shared__ __align__(16) float s_raw[8 * E];  // staging
  __shared__ __align__(16) float s_q2[64];
  __shared__ __align__(16) float s_attw[64];
  __shared__ __align__(16) float s_part[4][64];
  __shared__ int   s_tok[8];
  __shared__ float s_pv[16][8];
  __shared__ int   s_pi[16][8];

  const int tid  = threadIdx.x;
  const int lane = tid & 63;
  const int wv   = tid >> 6;          // wave 0..15
  const int bid  = blockIdx.x;
  int gen = 0;

  // ---- flag-slot grid barrier: 256 slots, parallel stores, 4 slots/lane poll ----
  auto gbar = [&]() {
    ++gen;
    __syncthreads();                  // drains each wave's stc (vmcnt 0)
    if (tid == 0) stci(&bar[bid * 32], gen);
    if (wv == 0) {
      for (;;) {
        int c0 = ldci(&bar[lane * 32]);
        int c1 = ldci(&bar[(lane + 64) * 32]);
        int c2 = ldci(&bar[(lane + 128) * 32]);
        int c3 = ldci(&bar[(lane + 192) * 32]);
        if (__all(c0 >= gen && c1 >= gen && c2 >= gen && c3 >= gen)) break;
        __builtin_amdgcn_s_sleep(1);
      }
    }
    __syncthreads();
  };

  auto stage_raw = [&](const float* src) {
    for (int k = tid; k < 2048; k += NT) {
      float2 vv = ldc8(src + 2 * k);
      s_raw[2 * k] = vv.x; s_raw[2 * k + 1] = vv.y;
    }
    __syncthreads();
  };
  // s_x[b] = LN(s_x[b] + s_raw[b]); waves 0-7 (b = wv); redundant per block
  auto lnstage = [&](int lnidx) {
    if (wv < 8) {
      const float* gg = ln_g + (size_t)lnidx * E;
      const float* be = ln_b + (size_t)lnidx * E;
      float v[8]; float sum = 0.f;
#pragma unroll
      for (int j = 0; j < 8; ++j) {
        int d = lane + 64 * j;
        v[j] = s_x[wv * E + d] + s_raw[wv * E + d];
        sum += v[j];
      }
      sum = wsum(sum);
      float mean = sum * (1.f / 512.f);
      float d2 = 0.f;
#pragma unroll
      for (int j = 0; j < 8; ++j) { float dd = v[j] - mean; d2 += dd * dd; }
      d2 = wsum(d2);
      float inv = 1.f / sqrtf(d2 * (1.f / 512.f) + 1e-5f);
#pragma unroll
      for (int j = 0; j < 8; ++j) {
        int d = lane + 64 * j;
        s_x[wv * E + d] = (v[j] - mean) * inv * gg[d] + be[d];
      }
    }
    __syncthreads();
  };
  // 2 rows (bid*2+j) x 8 batches from LDS src; one wsum per wave (16 waves)
  auto proj16 = [&](int wbase, const float* srcLDS, const float* biasp, float* dst) {
    int j = wv & 1, b = wv >> 1;
    int r = bid * 2 + j;
    const f4* wp = (const f4*)&s_w[wbase + j * 512];
    f4 w0 = wp[lane], w1 = wp[lane + 64];
    const f4* x4 = (const f4*)(srcLDS + b * E);
    f4 a = w0 * x4[lane] + w1 * x4[lane + 64];
    float acc = a.x + a.y + a.z + a.w;
    acc = wsum(acc);
    if (lane == 0) stc(&dst[b * E + r], acc + biasp[r]);
  };
  // attention (bid<64): b=bid>>3, h=bid&7; scores wave0, V-sum 4-way split
  auto attn_stage = [&](const float* Kbase, const float* Vbase, int nk) {
    const int b = bid >> 3, h = bid & 7;
    if (wv == 0) {
      s_q2[lane] = ldc(&qbuf[b * E + h * DH + lane]);
      float sc = -INFINITY;
      if (lane < nk) {
        const f4* Kr = (const f4*)(Kbase + ((size_t)lane * B + b) * E + h * DH);
        const f4* Qp = (const f4*)s_q2;
        float a0 = 0.f;
#pragma unroll
        for (int u = 0; u < 16; ++u) {
          f4 kv = Kr[u], qq = Qp[u];
          a0 += kv.x * qq.x + kv.y * qq.y + kv.z * qq.z + kv.w * qq.w;
        }
        sc = a0 * 0.125f;
      }
      float m = wmax(sc);
      float e = (lane < nk) ? expf(sc - m) : 0.f;
      float den = wsum(e);
      s_attw[lane] = e / den;
    }
    __syncthreads();
    if (wv < 4) {
      float o = 0.f;
      for (int k = wv; k < nk; k += 4)
        o = fmaf(s_attw[k], Vbase[((size_t)k * B + b) * E + h * DH + lane], o);
      s_part[wv][lane] = o;
    }
    __syncthreads();
    if (wv == 0)
      stc(&attbuf[b * E + h * DH + lane],
          s_part[0][lane] + s_part[1][lane] + s_part[2][lane] + s_part[3][lane]);
  };

  // ================= one-time: preload weight slices into LDS =================
  {
    auto cprow = [&](const float* src, int dstf) {
      f4* d = (f4*)&s_w[dstf]; const f4* s = (const f4*)src;
      for (int k = tid; k < 128; k += NT) d[k] = s[k];
    };
    for (int l = 0; l < NL; ++l) {
      for (int j = 0; j < 6; ++j)
        cprow(sa_w + ((size_t)l * 1536 + bid * 6 + j) * E, B_QKV + (l * 6 + j) * 512);
      for (int j = 0; j < 2; ++j) {
        cprow(sa_ow + ((size_t)l * 512 + bid * 2 + j) * E, B_OW + (l * 2 + j) * 512);
        cprow(ca_w + ((size_t)l * 1536 + bid * 2 + j) * E, B_CQ + (l * 2 + j) * 512);
        cprow(ca_ow + ((size_t)l * 512 + bid * 2 + j) * E, B_COW + (l * 2 + j) * 512);
      }
      for (int j = 0; j < 8; ++j)
        cprow(ff1_w + ((size_t)l * FF + bid * 8 + j) * E, B_FF1 + (l * 8 + j) * 512);
    }
    const int lf2 = bid >> 7;
    for (int j = 0; j < 4; ++j) {
      f4* d = (f4*)&s_w[B_FF2 + j * 2048];
      const f4* s = (const f4*)(ff2_w + ((size_t)lf2 * 512 + (bid & 127) * 4 + j) * FF);
      for (int k = tid; k < 512; k += NT) d[k] = s[k];
    }
    __syncthreads();
  }

  // ================= 23 autoregressive steps =================
  for (int i = 0; i < MAXLEN - 1; ++i) {
    const int p = INIT + i;

    // ---- token select + embed (ALL blocks redundant; no barrier needed) ----
    {
      int bw = wv & 7;
      float v = -INFINITY; int ix = 0x7fffffff;
      if (i == 0) {
        const float* row = outp + ((size_t)(INIT - 1) * B + bw) * V;
        for (int jj = lane; jj < V / 2; jj += 64) {
          float2 t = ldc8(row + 2 * jj);
          CMB(v, ix, t.x, 2 * jj);
          CMB(v, ix, t.y, 2 * jj + 1);
        }
      } else {
#pragma unroll
        for (int t = 0; t < 4; ++t) {
          int e = lane * 4 + t;
          float2 pr = ldc8(&amaxbuf[(size_t)(e * 8 + bw) * 2]);
          CMB(v, ix, pr.x, (int)pr.y);
        }
      }
#pragma unroll
      for (int off = 1; off < 64; off <<= 1) {
        float ov = __shfl_xor(v, off); int oi = __shfl_xor(ix, off);
        CMB(v, ix, ov, oi);
      }
      if (lane == 0 && wv < 8) s_tok[bw] = ix;
      __syncthreads();
      int b = tid >> 7, d0 = (tid & 127) * 4;
      int tok = s_tok[b];
      float4 ev = *(const float4*)(emb + (size_t)tok * E + d0);
      s_x[b * E + d0]     = ev.x;          // pe[0]: even +0
      s_x[b * E + d0 + 1] = ev.y + 1.0f;   // odd  +1
      s_x[b * E + d0 + 2] = ev.z;
      s_x[b * E + d0 + 3] = ev.w + 1.0f;
      __syncthreads();
    }

    for (int l = 0; l < NL; ++l) {
      // ---- S1: QKV (rows bid*6..+5) ----
      if (wv < 12) {
        int j = wv >> 1, bg = (wv & 1) * 4;
        int r = bid * 6 + j, sec = r >> 9, off = r & 511;
        const f4* wp = (const f4*)&s_w[B_QKV + (l * 6 + j) * 512];
        f4 w0 = wp[lane], w1 = wp[lane + 64];
        float bias = sa_b[(size_t)l * 1536 + r];
        for (int b = bg; b < bg + 4; ++b) {
          const f4* x4 = (const f4*)&s_x[b * E];
          f4 a = w0 * x4[lane] + w1 * x4[lane + 64];
          float acc = a.x + a.y + a.z + a.w;
          acc = wsum(acc);
          if (lane == 0) {
            acc += bias;
            if (sec == 0) stc(&qbuf[b * E + off], acc);
            else if (sec == 1) stc(&kself[((size_t)(l * LF + p) * B + b) * E + off], acc);
            else stc(&vself[((size_t)(l * LF + p) * B + b) * E + off], acc);
          }
        }
      }
      gbar();
      // ---- S2: self-attention ----
      if (bid < 64) attn_stage(kself + (size_t)l * LF * B * E, vself + (size_t)l * LF * B * E, p + 1);
      gbar();
      // ---- S3: self out-proj ----
      stage_raw(attbuf);
      proj16(B_OW + l * 1024, s_raw, sa_ob + (size_t)l * E, rawbuf);
      gbar();
      // ---- S4: x1 = LN(x + raw); cross-Q proj ----
      stage_raw(rawbuf);
      lnstage(l * 3 + 0);
      proj16(B_CQ + l * 1024, s_x, ca_b + (size_t)l * 3 * E, qbuf);
      gbar();
      // ---- S5: cross-attention ----
      if (bid < 64) attn_stage(kcross + (size_t)l * S * B * E, vcross + (size_t)l * S * B * E, S);
      gbar();
      // ---- S6: cross out-proj ----
      stage_raw(attbuf);
      proj16(B_COW + l * 1024, s_raw, ca_ob + (size_t)l * E, rawbuf);
      gbar();
      // ---- S7: x2 = LN(x1 + raw); ff1 (relu) ----
      stage_raw(rawbuf);
      lnstage(l * 3 + 1);
      {
        int j = wv >> 1, bg = (wv & 1) * 4;
        int r = bid * 8 + j;
        const f4* wp = (const f4*)&s_w[B_FF1 + (l * 8 + j) * 512];
        f4 w0 = wp[lane], w1 = wp[lane + 64];
        float bias = ff1_b[(size_t)l * FF + r];
        for (int b = bg; b < bg + 4; ++b) {
          const f4* x4 = (const f4*)&s_x[b * E];
          f4 a = w0 * x4[lane] + w1 * x4[lane + 64];
          float acc = a.x + a.y + a.z + a.w;
          acc = wsum(acc);
          if (lane == 0) stc(&hbuf[b * FF + r], fmaxf(acc + bias, 0.f));
        }
      }
      gbar();
      // ---- S8: ff2 (layer bid>>7, rows (bid&127)*4..+3, K=2048 from MALL) ----
      if ((bid >> 7) == l) {
        int b = wv >> 1, j0 = (wv & 1) * 2;
        int r0 = (bid & 127) * 4;
        f4 hv[8];
#pragma unroll
        for (int j = 0; j < 8; ++j) {
          const float* hp = hbuf + b * FF + (j * 64 + lane) * 4;
          float2 a = ldc8(hp), c = ldc8(hp + 2);
          hv[j].x = a.x; hv[j].y = a.y; hv[j].z = c.x; hv[j].w = c.y;
        }
#pragma unroll
        for (int jr = 0; jr < 2; ++jr) {
          int rl = j0 + jr;
          const f4* wp = (const f4*)&s_w[B_FF2 + rl * 2048];
          float acc = 0.f;
#pragma unroll
          for (int j = 0; j < 8; ++j) {
            f4 w = wp[j * 64 + lane];
            acc += w.x * hv[j].x + w.y * hv[j].y + w.z * hv[j].z + w.w * hv[j].w;
          }
          acc = wsum(acc);
          if (lane == 0)
            stc(&rawbuf[b * E + r0 + rl], acc + ff2_b[(size_t)l * 512 + r0 + rl]);
        }
      }
      gbar();
      // ---- x3/next-input = LN(x2 + y) (redundant, no barrier after) ----
      stage_raw(rawbuf);
      lnstage(l * 3 + 2);
    }

    // ---- logits (125 rows/block, plain cached out_w) + partial argmax ----
    {
      const int grp = lane >> 3, sub = lane & 7;
      const int idx = wv * 8 + grp;            // 0..127
      const bool valid = idx < 125;
      const int r = bid * 125 + idx;
      float acc[8] = {0, 0, 0, 0, 0, 0, 0, 0};
      if (valid) {
        const f4* wrow = (const f4*)(out_w + (size_t)r * E);
#pragma unroll
        for (int half = 0; half < 2; ++half) {
          f4 w8[8];
#pragma unroll
          for (int j = 0; j < 8; ++j) w8[j] = wrow[(half * 8 + j) * 8 + sub];
#pragma unroll
          for (int b = 0; b < 8; ++b) {
            const f4* x4 = (const f4*)&s_x[b * E];
            float a = 0.f;
#pragma unroll
            for (int j = 0; j < 8; ++j) {
              f4 xx = x4[(half * 8 + j) * 8 + sub];
              a += w8[j].x * xx.x + w8[j].y * xx.y + w8[j].z * xx.z + w8[j].w * xx.w;
            }
            acc[b] += a;
          }
        }
#pragma unroll
        for (int b = 0; b < 8; ++b) {
          acc[b] += __shfl_xor(acc[b], 1);
          acc[b] += __shfl_xor(acc[b], 2);
          acc[b] += __shfl_xor(acc[b], 4);
        }
        if (sub == 0) {
          float bo = out_b[r];
#pragma unroll
          for (int b = 0; b < 8; ++b) {
            acc[b] += bo;
            stc(&outp[((size_t)p * B + b) * V + r], acc[b]);
          }
        }
      }
#pragma unroll
      for (int b = 0; b < 8; ++b) {
        float v = (valid && sub == 0) ? acc[b] : -INFINITY;
        int ix = (valid && sub == 0) ? r : 0x7fffffff;
#pragma unroll
        for (int off = 1; off < 64; off <<= 1) {
          float ov = __shfl_xor(v, off); int oi = __shfl_xor(ix, off);
          CMB(v, ix, ov, oi);
        }
        if (lane == 0) { s_pv[wv][b] = v; s_pi[wv][b] = ix; }
      }
      __syncthreads();
      if (wv == 0) {
        int b = lane & 7, w2 = lane >> 3;      // w2 0..7
        float v = s_pv[w2][b]; int ix = s_pi[w2][b];
        float v2 = s_pv[w2 + 8][b]; int ix2 = s_pi[w2 + 8][b];
        CMB(v, ix, v2, ix2);
#pragma unroll
        for (int off = 8; off < 64; off <<= 1) {
          float ov = __shfl_xor(v, off); int oi = __shfl_xor(ix, off);
          CMB(v, ix, ov, oi);
        }
        if (lane < 8) stc8(&amaxbuf[(size_t)(bid * 8 + lane) * 2], v, (float)ix);
      }
    }
    gbar();
  }
}

extern "C" void kernel_launch(void* const* d_in, const int* in_sizes, int n_in,
                              void* d_out, int out_size, void* d_ws, size_t ws_size,
                              hipStream_t stream) {
  const float* enc       = (const float*)d_in[0];
  const int*   transform = (const int*)d_in[1];
  const float* emb       = (const float*)d_in[3];
  const float* sa_w  = (const float*)d_in[4];
  const float* sa_b  = (const float*)d_in[5];
  const float* sa_ow = (const float*)d_in[6];
  const float* sa_ob = (const float*)d_in[7];
  const float* ca_w  = (const float*)d_in[8];
  const float* ca_b  = (const float*)d_in[9];
  const float* ca_ow = (const float*)d_in[10];
  const float* ca_ob = (const float*)d_in[11];
  const float* ff1_w = (const float*)d_in[12];
  const float* ff1_b = (const float*)d_in[13];
  const float* ff2_w = (const float*)d_in[14];
  const float* ff2_b = (const float*)d_in[15];
  const float* ln_g  = (const float*)d_in[16];
  const float* ln_b  = (const float*)d_in[17];
  const float* out_w = (const float*)d_in[18];
  const float* out_b = (const float*)d_in[19];
  float* out = (float*)d_out;

  // workspace layout (floats)
  const size_t SELF_SZ  = (size_t)LF * B * E;    // 143360
  const size_t CROSS_SZ = (size_t)S * B * E;     // 196608
  float* ws     = (float*)d_ws;
  float* xbuf   = ws;                            // prefill embeddings [12*B, E]
  float* kself  = xbuf + (size_t)INIT * B * E;
  float* vself  = kself + NL * SELF_SZ;
  float* kcross = vself + NL * SELF_SZ;
  float* vcross = kcross + NL * CROSS_SZ;
  float* qbuf   = vcross + NL * CROSS_SZ;        // [8,512]
  float* attbuf = qbuf + 8 * E;
  float* rawbuf = attbuf + 8 * E;
  float* hbuf   = rawbuf + 8 * E;                // [8,2048]
  float* amaxb  = hbuf + 8 * FF;                 // [256,8,2]
  int*   bar    = (int*)(amaxb + 256 * 8 * 2);   // 256 slots x 128B
  float* act1   = (float*)(bar + 256 * 32);
  float* act2   = act1 + 96 * E;
  float* act3   = act2 + 96 * E;
  float* ffb    = act3 + 96 * E;                 // [96,FF]

  hipMemsetAsync(bar, 0, 256 * 32 * 4, stream);

  // 1) initial embeddings (positions 0..11)
  embed_init_k<<<INIT * B, 128, 0, stream>>>(transform, emb, xbuf);

  // 2) cross-attn K/V caches
  for (int l = 0; l < NL; ++l) {
    gemm_k<E><<<(2 * E) / 4, 256, 0, stream>>>(
        enc, ca_w + ((size_t)l * 3 * E + E) * E, ca_b + (size_t)l * 3 * E + E,
        S * B, 2 * E, 2, 0, kcross + l * CROSS_SZ, vcross + l * CROSS_SZ, nullptr);
  }

  // 3) prefill positions 0..11 (multi-kernel, one-time)
  {
    const int p0 = 0, nq = INIT, ntok = nq * B;
    const float* xin = xbuf;
    for (int l = 0; l < NL; ++l) {
      const float* x = (l == 0) ? xin : act1;
      gemm_k<E><<<(3 * E) / 4, 256, 0, stream>>>(
          x, sa_w + (size_t)l * 3 * E * E, sa_b + (size_t)l * 3 * E, ntok, 3 * E, 1, 0,
          act2, kself + l * SELF_SZ, vself + l * SELF_SZ);
      attn_k<<<nq * 16, 256, 0, stream>>>(act2, kself + l * SELF_SZ, vself + l * SELF_SZ,
                                          act3, p0, nq, 0, 1);
      gemm_k<E><<<E / 4, 256, 0, stream>>>(
          act3, sa_ow + (size_t)l * E * E, sa_ob + (size_t)l * E, ntok, E, 0, 0, act2, nullptr, nullptr);
      add_ln_k<<<(ntok + 3) / 4, 256, 0, stream>>>(
          x, act2, ln_g + (size_t)l * 3 * E, ln_b + (size_t)l * 3 * E, act1, ntok);
      gemm_k<E><<<E / 4, 256, 0, stream>>>(
          act1, ca_w + (size_t)l * 3 * E * E, ca_b + (size_t)l * 3 * E, ntok, E, 0, 0, act2, nullptr, nullptr);
      attn_k<<<nq * 16, 256, 0, stream>>>(act2, kcross + l * CROSS_SZ, vcross + l * CROSS_SZ,
                                          act3, p0, nq, S, 0);
      gemm_k<E><<<E / 4, 256, 0, stream>>>(
          act3, ca_ow + (size_t)l * E * E, ca_ob + (size_t)l * E, ntok, E, 0, 0, act2, nullptr, nullptr);
      add_ln_k<<<(ntok + 3) / 4, 256, 0, stream>>>(
          act1, act2, ln_g + (size_t)l * 3 * E + E, ln_b + (size_t)l * 3 * E + E, act1, ntok);
      gemm_k<E><<<FF / 4, 256, 0, stream>>>(
          act1, ff1_w + (size_t)l * FF * E, ff1_b + (size_t)l * FF, ntok, FF, 0, 1, ffb, nullptr, nullptr);
      gemm_k<FF><<<E / 4, 256, 0, stream>>>(
          ffb, ff2_w + (size_t)l * E * FF, ff2_b + (size_t)l * E, ntok, E, 0, 0, act2, nullptr, nullptr);
      add_ln_k<<<(ntok + 3) / 4, 256, 0, stream>>>(
          act1, act2, ln_g + (size_t)l * 3 * E + 2 * E, ln_b + (size_t)l * 3 * E + 2 * E, act1, ntok);
    }
    gemm_k<E><<<V / 4, 256, 0, stream>>>(
        act1, out_w, out_b, ntok, V, 0, 0, out, nullptr, nullptr);
  }

  // 4) persistent kernel: all 23 autoregressive steps
  decode_persist_k<<<NB, NT, 0, stream>>>(
      emb, sa_w, sa_b, sa_ow, sa_ob, ca_w, ca_b, ca_ow, ca_ob,
      ff1_w, ff1_b, ff2_w, ff2_b, ln_g, ln_b, out_w, out_b,
      kself, vself, kcross, vcross,
      qbuf, attbuf, rawbuf, hbuf, amaxb, out, bar);
}

// Round 8
// 4995.602 us; speedup vs baseline: 1.1055x; 1.0958x over previous
//
#include <hip/hip_runtime.h>
#include <hip/hip_bf16.h>
#include <math.h>

// ---- problem constants ----
#define V    32000
#define E    512
#define NH   8
#define DH   64
#define NL   2
#define FF   2048
#define MAXLEN 24
#define S    48
#define B    8
#define TRANS 14
#define INIT 12      // TRANS - 2
#define LF   35      // INIT + MAXLEN - 1

#define NB   256     // persistent grid blocks (1/CU, co-resident)
#define NT   1024    // threads per block (16 waves)

typedef float f4 __attribute__((ext_vector_type(4)));

__device__ inline float wsum(float v) {
#pragma unroll
  for (int off = 32; off; off >>= 1) v += __shfl_xor(v, off);
  return v;
}
__device__ inline float wmax(float v) {
#pragma unroll
  for (int off = 32; off; off >>= 1) v = fmaxf(v, __shfl_xor(v, off));
  return v;
}

// ---- write-through (relaxed agent) stores; readers use PLAIN cached loads of
// lines first-touched AFTER the write (rotated buffers; proven by K/V path r5-r7) ----
__device__ inline void stc(float* p, float v) {
  __hip_atomic_store(p, v, __ATOMIC_RELAXED, __HIP_MEMORY_SCOPE_AGENT);
}
__device__ inline void stc8(float* p, float x, float y) {
  union { unsigned long long u; float f[2]; } c; c.f[0] = x; c.f[1] = y;
  __hip_atomic_store((unsigned long long*)p, c.u, __ATOMIC_RELAXED, __HIP_MEMORY_SCOPE_AGENT);
}
__device__ inline int ldci(const int* p) {
  return __hip_atomic_load(p, __ATOMIC_RELAXED, __HIP_MEMORY_SCOPE_AGENT);
}
__device__ inline void stci(int* p, int v) {
  __hip_atomic_store(p, v, __ATOMIC_RELAXED, __HIP_MEMORY_SCOPE_AGENT);
}

#define CMB(v, idx, ov, oi) do { if ((ov) > (v) || ((ov) == (v) && (oi) < (idx))) { (v) = (ov); (idx) = (oi); } } while (0)

// ================= prefill kernels (rounds 1-7, proven) =================

__global__ void embed_init_k(const int* __restrict__ transform, const float* __restrict__ emb,
                             float* __restrict__ xbuf) {
  int t = blockIdx.x;
  int pos = t >> 3, b = t & 7;
  int tok = transform[(1 + pos) * B + b];
  for (int d = threadIdx.x; d < E; d += blockDim.x) {
    double div = exp(-log(10000.0) * (double)(d & ~1) / (double)E);
    double ang = (double)pos * div;
    float pe = (d & 1) ? (float)cos(ang) : (float)sin(ang);
    xbuf[(size_t)t * E + d] = emb[(size_t)tok * E + d] + pe;
  }
}

template <int K>
__global__ __launch_bounds__(256) void gemm_k(
    const float* __restrict__ x, const float* __restrict__ W, const float* __restrict__ bias,
    int ntok, int nout, int route, int relu,
    float* __restrict__ out0, float* __restrict__ out1, float* __restrict__ out2) {
  constexpr int K4 = K / 4;
  constexpr int J  = K / 256;
  __shared__ float4 xt[8][K4];
  const int tid = threadIdx.x;
  const int lane = tid & 63;
  const int o = blockIdx.x * 4 + (tid >> 6);

  float4 wr[J];
  if (o < nout) {
    const float4* Wr = (const float4*)(W + (size_t)o * K);
#pragma unroll
    for (int j = 0; j < J; ++j) wr[j] = Wr[lane + 64 * j];
  }

  const int ng = ntok >> 3;
  for (int g = 0; g < ng; ++g) {
    if (g) __syncthreads();
    const float4* xg = (const float4*)(x + (size_t)g * 8 * K);
    float4* xf = &xt[0][0];
    for (int i = tid; i < 8 * K4; i += 256) xf[i] = xg[i];
    __syncthreads();
    if (o < nout) {
      float acc[8] = {0, 0, 0, 0, 0, 0, 0, 0};
#pragma unroll
      for (int j = 0; j < J; ++j) {
        float4 w = wr[j];
#pragma unroll
        for (int tt = 0; tt < 8; ++tt) {
          float4 xv = xt[tt][lane + 64 * j];
          acc[tt] += w.x * xv.x + w.y * xv.y + w.z * xv.z + w.w * xv.w;
        }
      }
#pragma unroll
      for (int tt = 0; tt < 8; ++tt) acc[tt] = wsum(acc[tt]);
      if (lane == 0) {
        float bo = bias[o];
#pragma unroll
        for (int tt = 0; tt < 8; ++tt) {
          float v = acc[tt] + bo;
          if (relu) v = fmaxf(v, 0.f);
          int t = g * 8 + tt;
          if (route == 0) {
            out0[(size_t)t * nout + o] = v;
          } else if (route == 1) {
            if (o < E) out0[(size_t)t * E + o] = v;
            else if (o < 2 * E) out1[(size_t)t * E + (o - E)] = v;
            else out2[(size_t)t * E + (o - 2 * E)] = v;
          } else {
            if (o < E) out0[(size_t)t * E + o] = v;
            else out1[(size_t)t * E + (o - E)] = v;
          }
        }
      }
    }
  }
}

__global__ __launch_bounds__(256) void attn_k(
    const float* __restrict__ q, const float* __restrict__ Kc, const float* __restrict__ Vc,
    float* __restrict__ outp, int p0, int nq, int nk_fixed, int causal) {
  const int tid = threadIdx.x;
  const int lane = tid & 63;
  const int u = blockIdx.x * 4 + (tid >> 6);
  if (u >= nq * 64) return;
  const int qi = u >> 6;
  const int r = u & 63;
  const int b = r >> 3, h = r & 7;
  const int nk = causal ? (p0 + qi + 1) : nk_fixed;

  const size_t qoff = (size_t)(qi * B + b) * E + h * DH + lane;
  const float qv = q[qoff];

  float myscore = -INFINITY;
  for (int k = 0; k < nk; ++k) {
    float prod = qv * Kc[(size_t)(k * B + b) * E + h * DH + lane];
    prod = wsum(prod);
    if (lane == k) myscore = prod * 0.125f;
  }
  float m = wmax(myscore);
  float p = (lane < nk) ? expf(myscore - m) : 0.f;
  float denom = wsum(p);
  float a = p / denom;

  float oacc = 0.f;
  for (int k = 0; k < nk; ++k) {
    float ak = __shfl(a, k);
    oacc = fmaf(ak, Vc[(size_t)(k * B + b) * E + h * DH + lane], oacc);
  }
  outp[qoff] = oacc;
}

__global__ __launch_bounds__(256) void add_ln_k(
    const float* __restrict__ xa, const float* __restrict__ xb,
    const float* __restrict__ g, const float* __restrict__ beta,
    float* __restrict__ outp, int ntok) {
  const int tid = threadIdx.x, lane = tid & 63;
  const int t = blockIdx.x * 4 + (tid >> 6);
  if (t >= ntok) return;
  float v[8];
  float s = 0.f;
#pragma unroll
  for (int j = 0; j < 8; ++j) {
    int d = lane + 64 * j;
    v[j] = xa[(size_t)t * E + d] + xb[(size_t)t * E + d];
    s += v[j];
  }
  s = wsum(s);
  float mean = s * (1.f / 512.f);
  float d2 = 0.f;
#pragma unroll
  for (int j = 0; j < 8; ++j) { float dd = v[j] - mean; d2 += dd * dd; }
  d2 = wsum(d2);
  float inv = 1.f / sqrtf(d2 * (1.f / 512.f) + 1e-5f);
#pragma unroll
  for (int j = 0; j < 8; ++j) {
    int d = lane + 64 * j;
    outp[(size_t)t * E + d] = (v[j] - mean) * inv * g[d] + beta[d];
  }
}

// ================= persistent decode v5 =================
// LDS-resident weights + rotated per-(step,stage) buffers with cached broadcast
// reads + master-release barrier. 17 barriers/step.
#define B_QKV 0        // 2l x 6 rows x 512
#define B_OW  6144     // 2l x 2 rows x 512
#define B_CQ  8192     // 2l x 2 rows x 512
#define B_COW 10240    // 2l x 2 rows x 512
#define B_FF1 12288    // 2l x 8 rows x 512
#define B_FF2 20480    // 4 rows x 2048 (layer = bid>>7)
#define SW_TOT 28672
#define SLOTS_PER_STEP 23

__global__ __launch_bounds__(NT, 1) void decode_persist_k(
    const float* __restrict__ emb,
    const float* __restrict__ sa_w, const float* __restrict__ sa_b,
    const float* __restrict__ sa_ow, const float* __restrict__ sa_ob,
    const float* __restrict__ ca_w, const float* __restrict__ ca_b,
    const float* __restrict__ ca_ow, const float* __restrict__ ca_ob,
    const float* __restrict__ ff1_w, const float* __restrict__ ff1_b,
    const float* __restrict__ ff2_w, const float* __restrict__ ff2_b,
    const float* __restrict__ ln_g, const float* __restrict__ ln_b,
    const float* __restrict__ out_w, const float* __restrict__ out_b,
    float* __restrict__ kself, float* __restrict__ vself,
    const float* __restrict__ kcross, const float* __restrict__ vcross,
    float* __restrict__ arena, float* __restrict__ outp, int* __restrict__ bar) {
  __shared__ __align__(16) float s_w[SW_TOT];   // 112 KB weight slice
  __shared__ __align__(16) float s_x[8 * E];    // residual stream (persistent)
  __shared__ __align__(16) float s_raw[8 * E];  // staging
  __shared__ __align__(16) float s_q2[64];
  __shared__ __align__(16) float s_attw[64];
  __shared__ __align__(16) float s_part[4][64];
  __shared__ int   s_tok[8];
  __shared__ float s_pv[16][8];
  __shared__ int   s_pi[16][8];

  const int tid  = threadIdx.x;
  const int lane = tid & 63;
  const int wv   = tid >> 6;          // wave 0..15
  const int bid  = blockIdx.x;
  int gen = 0;

  // slot(st, s): 16 KB (4096-float) rotated buffer
  auto slot = [&](int st, int s) -> float* {
    return arena + ((size_t)st * SLOTS_PER_STEP + s) * 4096;
  };

  // ---- master-release grid barrier ----
  auto gbar = [&]() {
    ++gen;
    __syncthreads();                  // drains each wave's stores (vmcnt 0)
    if (tid == 0)
      __hip_atomic_fetch_add(&bar[(bid & 31) * 32], 1, __ATOMIC_RELAXED, __HIP_MEMORY_SCOPE_AGENT);
    if (bid == 0 && wv == 0) {
      const int tgt = gen * 8;        // 8 blocks per shard
      for (;;) {
        int c = (lane < 32) ? ldci(&bar[lane * 32]) : tgt;
        if (__all(c >= tgt)) break;
        __builtin_amdgcn_s_sleep(1);
      }
      if (lane == 0) stci(&bar[40 * 32], gen);
    }
    if (wv == 0) {
      while (ldci(&bar[40 * 32]) < gen) __builtin_amdgcn_s_sleep(2);
    }
    __syncthreads();
  };

  // ---- stage a [8][512] set into LDS via PLAIN cached loads ----
  auto stage_raw = [&](const float* src) {
    const float4* s4 = (const float4*)src;
    float4* d4 = (float4*)s_raw;
    for (int k = tid; k < 1024; k += NT) d4[k] = s4[k];
    __syncthreads();
  };
  // s_x[b] = LN(s_x[b] + s_raw[b]); waves 0-7 (b = wv); redundant per block
  auto lnstage = [&](int lnidx) {
    if (wv < 8) {
      const float* gg = ln_g + (size_t)lnidx * E;
      const float* be = ln_b + (size_t)lnidx * E;
      float v[8]; float sum = 0.f;
#pragma unroll
      for (int j = 0; j < 8; ++j) {
        int d = lane + 64 * j;
        v[j] = s_x[wv * E + d] + s_raw[wv * E + d];
        sum += v[j];
      }
      sum = wsum(sum);
      float mean = sum * (1.f / 512.f);
      float d2 = 0.f;
#pragma unroll
      for (int j = 0; j < 8; ++j) { float dd = v[j] - mean; d2 += dd * dd; }
      d2 = wsum(d2);
      float inv = 1.f / sqrtf(d2 * (1.f / 512.f) + 1e-5f);
#pragma unroll
      for (int j = 0; j < 8; ++j) {
        int d = lane + 64 * j;
        s_x[wv * E + d] = (v[j] - mean) * inv * gg[d] + be[d];
      }
    }
    __syncthreads();
  };
  // 2 rows (bid*2+j) x 8 batches from LDS src; 16 waves
  auto proj16 = [&](int wbase, const float* srcLDS, const float* biasp, float* dst) {
    int j = wv & 1, b = wv >> 1;
    int r = bid * 2 + j;
    const f4* wp = (const f4*)&s_w[wbase + j * 512];
    f4 w0 = wp[lane], w1 = wp[lane + 64];
    const f4* x4 = (const f4*)(srcLDS + b * E);
    f4 a = w0 * x4[lane] + w1 * x4[lane + 64];
    float acc = a.x + a.y + a.z + a.w;
    acc = wsum(acc);
    if (lane == 0) stc(&dst[b * E + r], acc + biasp[r]);
  };
  // attention (bid<64): b=bid>>3, h=bid&7; q from qsrc (cached), out -> attdst (stc)
  auto attn_stage = [&](const float* qsrc, const float* Kbase, const float* Vbase,
                        int nk, float* attdst) {
    const int b = bid >> 3, h = bid & 7;
    if (wv == 0) {
      s_q2[lane] = qsrc[b * E + h * DH + lane];
      float sc = -INFINITY;
      if (lane < nk) {
        const f4* Kr = (const f4*)(Kbase + ((size_t)lane * B + b) * E + h * DH);
        const f4* Qp = (const f4*)s_q2;
        float a0 = 0.f;
#pragma unroll
        for (int u = 0; u < 16; ++u) {
          f4 kv = Kr[u], qq = Qp[u];
          a0 += kv.x * qq.x + kv.y * qq.y + kv.z * qq.z + kv.w * qq.w;
        }
        sc = a0 * 0.125f;
      }
      float m = wmax(sc);
      float e = (lane < nk) ? expf(sc - m) : 0.f;
      float den = wsum(e);
      s_attw[lane] = e / den;
    }
    __syncthreads();
    if (wv < 4) {
      float o = 0.f;
      for (int k = wv; k < nk; k += 4)
        o = fmaf(s_attw[k], Vbase[((size_t)k * B + b) * E + h * DH + lane], o);
      s_part[wv][lane] = o;
    }
    __syncthreads();
    if (wv == 0)
      stc(&attdst[b * E + h * DH + lane],
          s_part[0][lane] + s_part[1][lane] + s_part[2][lane] + s_part[3][lane]);
  };

  // ================= one-time: preload weight slices into LDS =================
  {
    auto cprow = [&](const float* src, int dstf) {
      f4* d = (f4*)&s_w[dstf]; const f4* s = (const f4*)src;
      for (int k = tid; k < 128; k += NT) d[k] = s[k];
    };
    for (int l = 0; l < NL; ++l) {
      for (int j = 0; j < 6; ++j)
        cprow(sa_w + ((size_t)l * 1536 + bid * 6 + j) * E, B_QKV + (l * 6 + j) * 512);
      for (int j = 0; j < 2; ++j) {
        cprow(sa_ow + ((size_t)l * 512 + bid * 2 + j) * E, B_OW + (l * 2 + j) * 512);
        cprow(ca_w + ((size_t)l * 1536 + bid * 2 + j) * E, B_CQ + (l * 2 + j) * 512);
        cprow(ca_ow + ((size_t)l * 512 + bid * 2 + j) * E, B_COW + (l * 2 + j) * 512);
      }
      for (int j = 0; j < 8; ++j)
        cprow(ff1_w + ((size_t)l * FF + bid * 8 + j) * E, B_FF1 + (l * 8 + j) * 512);
    }
    const int lf2 = bid >> 7;
    for (int j = 0; j < 4; ++j) {
      f4* d = (f4*)&s_w[B_FF2 + j * 2048];
      const f4* s = (const f4*)(ff2_w + ((size_t)lf2 * 512 + (bid & 127) * 4 + j) * FF);
      for (int k = tid; k < 512; k += NT) d[k] = s[k];
    }
    __syncthreads();
  }

  // ================= 23 autoregressive steps =================
  for (int i = 0; i < MAXLEN - 1; ++i) {
    const int p = INIT + i;
    float* amax_o = slot(i, 0);

    // ---- token select + embed (all blocks redundant; cached reads) ----
    {
      int bw = wv & 7;
      float v = -INFINITY; int ix = 0x7fffffff;
      if (i == 0) {
        const float2* row = (const float2*)(outp + ((size_t)(INIT - 1) * B + bw) * V);
        for (int jj = lane; jj < V / 2; jj += 64) {
          float2 t = row[jj];
          CMB(v, ix, t.x, 2 * jj);
          CMB(v, ix, t.y, 2 * jj + 1);
        }
      } else {
        const float2* ap = (const float2*)slot(i - 1, 0);
#pragma unroll
        for (int t = 0; t < 4; ++t) {
          int e = lane * 4 + t;
          float2 pr = ap[e * 8 + bw];
          CMB(v, ix, pr.x, (int)pr.y);
        }
      }
#pragma unroll
      for (int off = 1; off < 64; off <<= 1) {
        float ov = __shfl_xor(v, off); int oi = __shfl_xor(ix, off);
        CMB(v, ix, ov, oi);
      }
      if (lane == 0 && wv < 8) s_tok[bw] = ix;
      __syncthreads();
      int b = tid >> 7, d0 = (tid & 127) * 4;
      int tok = s_tok[b];
      float4 ev = *(const float4*)(emb + (size_t)tok * E + d0);
      s_x[b * E + d0]     = ev.x;          // pe[0]: even +0
      s_x[b * E + d0 + 1] = ev.y + 1.0f;   // odd  +1
      s_x[b * E + d0 + 2] = ev.z;
      s_x[b * E + d0 + 3] = ev.w + 1.0f;
      __syncthreads();
    }

    for (int l = 0; l < NL; ++l) {
      float* Lb    = slot(i, 1 + l * 11);
      float* q_s   = Lb;                 // self q
      float* att_s = Lb + 4096;
      float* raw_s = Lb + 8192;
      float* q_c   = Lb + 12288;
      float* att_c = Lb + 16384;
      float* raw_c = Lb + 20480;
      float* hb    = Lb + 24576;         // [8][2048] (4 slots)
      float* yb    = Lb + 40960;

      // ---- S1: QKV (rows bid*6..+5) ----
      if (wv < 12) {
        int j = wv >> 1, bg = (wv & 1) * 4;
        int r = bid * 6 + j, sec = r >> 9, off = r & 511;
        const f4* wp = (const f4*)&s_w[B_QKV + (l * 6 + j) * 512];
        f4 w0 = wp[lane], w1 = wp[lane + 64];
        float bias = sa_b[(size_t)l * 1536 + r];
        for (int b = bg; b < bg + 4; ++b) {
          const f4* x4 = (const f4*)&s_x[b * E];
          f4 a = w0 * x4[lane] + w1 * x4[lane + 64];
          float acc = a.x + a.y + a.z + a.w;
          acc = wsum(acc);
          if (lane == 0) {
            acc += bias;
            if (sec == 0) stc(&q_s[b * E + off], acc);
            else if (sec == 1) stc(&kself[((size_t)(l * LF + p) * B + b) * E + off], acc);
            else stc(&vself[((size_t)(l * LF + p) * B + b) * E + off], acc);
          }
        }
      }
      gbar();
      // ---- S2: self-attention ----
      if (bid < 64)
        attn_stage(q_s, kself + (size_t)l * LF * B * E, vself + (size_t)l * LF * B * E,
                   p + 1, att_s);
      gbar();
      // ---- S3: self out-proj ----
      stage_raw(att_s);
      proj16(B_OW + l * 1024, s_raw, sa_ob + (size_t)l * E, raw_s);
      gbar();
      // ---- S4: x1 = LN(x + raw); cross-Q proj ----
      stage_raw(raw_s);
      lnstage(l * 3 + 0);
      proj16(B_CQ + l * 1024, s_x, ca_b + (size_t)l * 3 * E, q_c);
      gbar();
      // ---- S5: cross-attention ----
      if (bid < 64)
        attn_stage(q_c, kcross + (size_t)l * S * B * E, vcross + (size_t)l * S * B * E,
                   S, att_c);
      gbar();
      // ---- S6: cross out-proj ----
      stage_raw(att_c);
      proj16(B_COW + l * 1024, s_raw, ca_ob + (size_t)l * E, raw_c);
      gbar();
      // ---- S7: x2 = LN(x1 + raw); ff1 (relu) ----
      stage_raw(raw_c);
      lnstage(l * 3 + 1);
      {
        int j = wv >> 1, bg = (wv & 1) * 4;
        int r = bid * 8 + j;
        const f4* wp = (const f4*)&s_w[B_FF1 + (l * 8 + j) * 512];
        f4 w0 = wp[lane], w1 = wp[lane + 64];
        float bias = ff1_b[(size_t)l * FF + r];
        for (int b = bg; b < bg + 4; ++b) {
          const f4* x4 = (const f4*)&s_x[b * E];
          f4 a = w0 * x4[lane] + w1 * x4[lane + 64];
          float acc = a.x + a.y + a.z + a.w;
          acc = wsum(acc);
          if (lane == 0) stc(&hb[b * FF + r], fmaxf(acc + bias, 0.f));
        }
      }
      gbar();
      // ---- S8: ff2 (layer bid>>7, rows (bid&127)*4..+3, K=2048 cached) ----
      if ((bid >> 7) == l) {
        int b = wv >> 1, j0 = (wv & 1) * 2;
        int r0 = (bid & 127) * 4;
        const f4* h4 = (const f4*)(hb + b * FF);
        f4 hv[8];
#pragma unroll
        for (int j = 0; j < 8; ++j) hv[j] = h4[j * 64 + lane];
#pragma unroll
        for (int jr = 0; jr < 2; ++jr) {
          int rl = j0 + jr;
          const f4* wp = (const f4*)&s_w[B_FF2 + rl * 2048];
          float acc = 0.f;
#pragma unroll
          for (int j = 0; j < 8; ++j) {
            f4 w = wp[j * 64 + lane];
            acc += w.x * hv[j].x + w.y * hv[j].y + w.z * hv[j].z + w.w * hv[j].w;
          }
          acc = wsum(acc);
          if (lane == 0)
            stc(&yb[b * E + r0 + rl], acc + ff2_b[(size_t)l * 512 + r0 + rl]);
        }
      }
      gbar();
      // ---- x3/next-input = LN(x2 + y) (redundant, no barrier after) ----
      stage_raw(yb);
      lnstage(l * 3 + 2);
    }

    // ---- logits (125 rows/block, cached out_w, PLAIN stores) + partial argmax ----
    {
      const int grp = lane >> 3, sub = lane & 7;
      const int idx = wv * 8 + grp;            // 0..127
      const bool valid = idx < 125;
      const int r = bid * 125 + idx;
      float acc[8] = {0, 0, 0, 0, 0, 0, 0, 0};
      if (valid) {
        const f4* wrow = (const f4*)(out_w + (size_t)r * E);
#pragma unroll
        for (int half = 0; half < 2; ++half) {
          f4 w8[8];
#pragma unroll
          for (int j = 0; j < 8; ++j) w8[j] = wrow[(half * 8 + j) * 8 + sub];
#pragma unroll
          for (int b = 0; b < 8; ++b) {
            const f4* x4 = (const f4*)&s_x[b * E];
            float a = 0.f;
#pragma unroll
            for (int j = 0; j < 8; ++j) {
              f4 xx = x4[(half * 8 + j) * 8 + sub];
              a += w8[j].x * xx.x + w8[j].y * xx.y + w8[j].z * xx.z + w8[j].w * xx.w;
            }
            acc[b] += a;
          }
        }
#pragma unroll
        for (int b = 0; b < 8; ++b) {
          acc[b] += __shfl_xor(acc[b], 1);
          acc[b] += __shfl_xor(acc[b], 2);
          acc[b] += __shfl_xor(acc[b], 4);
        }
        if (sub == 0) {
          float bo = out_b[r];
#pragma unroll
          for (int b = 0; b < 8; ++b) {
            acc[b] += bo;
            outp[((size_t)p * B + b) * V + r] = acc[b];   // host-only reader
          }
        }
      }
#pragma unroll
      for (int b = 0; b < 8; ++b) {
        float v = (valid && sub == 0) ? acc[b] : -INFINITY;
        int ix = (valid && sub == 0) ? r : 0x7fffffff;
#pragma unroll
        for (int off = 1; off < 64; off <<= 1) {
          float ov = __shfl_xor(v, off); int oi = __shfl_xor(ix, off);
          CMB(v, ix, ov, oi);
        }
        if (lane == 0) { s_pv[wv][b] = v; s_pi[wv][b] = ix; }
      }
      __syncthreads();
      if (wv == 0) {
        int b = lane & 7, w2 = lane >> 3;      // w2 0..7
        float v = s_pv[w2][b]; int ix = s_pi[w2][b];
        float v2 = s_pv[w2 + 8][b]; int ix2 = s_pi[w2 + 8][b];
        CMB(v, ix, v2, ix2);
#pragma unroll
        for (int off = 8; off < 64; off <<= 1) {
          float ov = __shfl_xor(v, off); int oi = __shfl_xor(ix, off);
          CMB(v, ix, ov, oi);
        }
        if (lane < 8) stc8(&amax_o[(size_t)(bid * 8 + lane) * 2], v, (float)ix);
      }
    }
    gbar();
  }
}

extern "C" void kernel_launch(void* const* d_in, const int* in_sizes, int n_in,
                              void* d_out, int out_size, void* d_ws, size_t ws_size,
                              hipStream_t stream) {
  const float* enc       = (const float*)d_in[0];
  const int*   transform = (const int*)d_in[1];
  const float* emb       = (const float*)d_in[3];
  const float* sa_w  = (const float*)d_in[4];
  const float* sa_b  = (const float*)d_in[5];
  const float* sa_ow = (const float*)d_in[6];
  const float* sa_ob = (const float*)d_in[7];
  const float* ca_w  = (const float*)d_in[8];
  const float* ca_b  = (const float*)d_in[9];
  const float* ca_ow = (const float*)d_in[10];
  const float* ca_ob = (const float*)d_in[11];
  const float* ff1_w = (const float*)d_in[12];
  const float* ff1_b = (const float*)d_in[13];
  const float* ff2_w = (const float*)d_in[14];
  const float* ff2_b = (const float*)d_in[15];
  const float* ln_g  = (const float*)d_in[16];
  const float* ln_b  = (const float*)d_in[17];
  const float* out_w = (const float*)d_in[18];
  const float* out_b = (const float*)d_in[19];
  float* out = (float*)d_out;

  // workspace layout (floats)
  const size_t SELF_SZ  = (size_t)LF * B * E;    // 143360
  const size_t CROSS_SZ = (size_t)S * B * E;     // 196608
  const size_t ARENA_SZ = (size_t)(MAXLEN - 1) * SLOTS_PER_STEP * 4096;  // 8.7 MB
  float* ws     = (float*)d_ws;
  float* xbuf   = ws;                            // prefill embeddings [12*B, E]
  float* kself  = xbuf + (size_t)INIT * B * E;
  float* vself  = kself + NL * SELF_SZ;
  float* kcross = vself + NL * SELF_SZ;
  float* vcross = kcross + NL * CROSS_SZ;
  float* arena  = vcross + NL * CROSS_SZ;
  int*   bar    = (int*)(arena + ARENA_SZ);      // 64 slots x 128B
  float* act1   = (float*)(bar + 64 * 32);
  float* act2   = act1 + 96 * E;
  float* act3   = act2 + 96 * E;
  float* ffb    = act3 + 96 * E;                 // [96,FF]

  hipMemsetAsync(bar, 0, 64 * 32 * 4, stream);

  // 1) initial embeddings (positions 0..11)
  embed_init_k<<<INIT * B, 128, 0, stream>>>(transform, emb, xbuf);

  // 2) cross-attn K/V caches
  for (int l = 0; l < NL; ++l) {
    gemm_k<E><<<(2 * E) / 4, 256, 0, stream>>>(
        enc, ca_w + ((size_t)l * 3 * E + E) * E, ca_b + (size_t)l * 3 * E + E,
        S * B, 2 * E, 2, 0, kcross + l * CROSS_SZ, vcross + l * CROSS_SZ, nullptr);
  }

  // 3) prefill positions 0..11 (multi-kernel, one-time)
  {
    const int p0 = 0, nq = INIT, ntok = nq * B;
    const float* xin = xbuf;
    for (int l = 0; l < NL; ++l) {
      const float* x = (l == 0) ? xin : act1;
      gemm_k<E><<<(3 * E) / 4, 256, 0, stream>>>(
          x, sa_w + (size_t)l * 3 * E * E, sa_b + (size_t)l * 3 * E, ntok, 3 * E, 1, 0,
          act2, kself + l * SELF_SZ, vself + l * SELF_SZ);
      attn_k<<<nq * 16, 256, 0, stream>>>(act2, kself + l * SELF_SZ, vself + l * SELF_SZ,
                                          act3, p0, nq, 0, 1);
      gemm_k<E><<<E / 4, 256, 0, stream>>>(
          act3, sa_ow + (size_t)l * E * E, sa_ob + (size_t)l * E, ntok, E, 0, 0, act2, nullptr, nullptr);
      add_ln_k<<<(ntok + 3) / 4, 256, 0, stream>>>(
          x, act2, ln_g + (size_t)l * 3 * E, ln_b + (size_t)l * 3 * E, act1, ntok);
      gemm_k<E><<<E / 4, 256, 0, stream>>>(
          act1, ca_w + (size_t)l * 3 * E * E, ca_b + (size_t)l * 3 * E, ntok, E, 0, 0, act2, nullptr, nullptr);
      attn_k<<<nq * 16, 256, 0, stream>>>(act2, kcross + l * CROSS_SZ, vcross + l * CROSS_SZ,
                                          act3, p0, nq, S, 0);
      gemm_k<E><<<E / 4, 256, 0, stream>>>(
          act3, ca_ow + (size_t)l * E * E, ca_ob + (size_t)l * E, ntok, E, 0, 0, act2, nullptr, nullptr);
      add_ln_k<<<(ntok + 3) / 4, 256, 0, stream>>>(
          act1, act2, ln_g + (size_t)l * 3 * E + E, ln_b + (size_t)l * 3 * E + E, act1, ntok);
      gemm_k<E><<<FF / 4, 256, 0, stream>>>(
          act1, ff1_w + (size_t)l * FF * E, ff1_b + (size_t)l * FF, ntok, FF, 0, 1, ffb, nullptr, nullptr);
      gemm_k<FF><<<E / 4, 256, 0, stream>>>(
          ffb, ff2_w + (size_t)l * E * FF, ff2_b + (size_t)l * E, ntok, E, 0, 0, act2, nullptr, nullptr);
      add_ln_k<<<(ntok + 3) / 4, 256, 0, stream>>>(
          act1, act2, ln_g + (size_t)l * 3 * E + 2 * E, ln_b + (size_t)l * 3 * E + 2 * E, act1, ntok);
    }
    gemm_k<E><<<V / 4, 256, 0, stream>>>(
        act1, out_w, out_b, ntok, V, 0, 0, out, nullptr, nullptr);
  }

  // 4) persistent kernel: all 23 autoregressive steps
  decode_persist_k<<<NB, NT, 0, stream>>>(
      emb, sa_w, sa_b, sa_ow, sa_ob, ca_w, ca_b, ca_ow, ca_ob,
      ff1_w, ff1_b, ff2_w, ff2_b, ln_g, ln_b, out_w, out_b,
      kself, vself, kcross, vcross, arena, out, bar);
}